// Round 5
// baseline (132.421 us; speedup 1.0000x reference)
//
#include <hip/hip_runtime.h>

#define T_LEN 2048
#define NMODE 8
#define NPP   17   // 8 tau + 9 g (g[0]=g_infy, g[1..8]=g_i)

// ---------------------------------------------------------------------------
// Fused scan phase. Thread = (b, c, eg) where eg indexes a group of 3 tensor
// entries (e = 3*eg .. 3*eg+2). Each thread carries Q[mode][3] and computes
// the per-mode coefficients ONCE per 3 entries (was once per 1).
// Folded algebra: ee = exp(-0.5*dt/tau_bar) = exp(-dt/(tau_c+tau_p)).
//   PHASE3=false: from zero state, emit R[b,e,c,m] and P[b,c,m] (eg==0).
//   PHASE3=true : R holds per-chunk entry states Z; rerun, write outputs.
// R layout [b,e,c,m]: ((b*9+e)*NC + c)*8 + m (32B-aligned, chunk-contiguous).
// ---------------------------------------------------------------------------
template <int L, bool PHASE3>
__global__ __launch_bounds__(128)
void scan_fused3(const float* __restrict__ Se,   // [B,T,3,3]
                 const float* __restrict__ tt,   // [B,T]
                 const float* __restrict__ pp,   // [B,T,17]
                 float* __restrict__ R,          // [B,9,NC,8]
                 float* __restrict__ P,          // [B,NC,8]
                 float* __restrict__ out,        // [3,B,T,3,3]
                 int B) {
    constexpr int NC = T_LEN / L;
    int tid = blockIdx.x * blockDim.x + threadIdx.x;
    int total = B * NC * 3;
    if (tid >= total) return;
    int eg = tid % 3;
    int bc = tid / 3;
    int c  = bc % NC;
    int b  = bc / NC;
    int t0 = c * L;
    int e0 = eg * 3;

    // ---- previous-row state ----
    float tau_p[NMODE], g_p[NMODE];
    float inv_p, t_p, S_p[3];
    {
        int prow = (t0 == 0) ? 0 : (t0 - 1);
        size_t row = (size_t)b * T_LEN + prow;
        const float* p = pp + row * NPP;
        #pragma unroll
        for (int m = 0; m < NMODE; ++m) tau_p[m] = p[m];
        float g8 = p[8];
        #pragma unroll
        for (int m = 0; m < NMODE; ++m) g_p[m] = p[9 + m];
        float gsum = g8;
        #pragma unroll
        for (int m = 0; m < NMODE; ++m) gsum += g_p[m];
        inv_p = __builtin_amdgcn_rcpf(gsum);
        t_p = (t0 == 0) ? -tt[(size_t)b * T_LEN + 1] : tt[row];
        if (t0 == 0) {
            S_p[0] = S_p[1] = S_p[2] = 0.f;
        } else {
            const float* sp = Se + row * 9 + e0;
            S_p[0] = sp[0]; S_p[1] = sp[1]; S_p[2] = sp[2];
        }
    }

    // ---- recurrence state ----
    float Q[NMODE][3], Pp[NMODE];
    if (PHASE3) {
        #pragma unroll
        for (int j = 0; j < 3; ++j) {
            size_t rb = ((size_t)(b * 9 + e0 + j) * NC + (size_t)c) * NMODE;
            const float4* rz = (const float4*)(R + rb);
            float4 z0 = rz[0], z1 = rz[1];
            Q[0][j]=z0.x; Q[1][j]=z0.y; Q[2][j]=z0.z; Q[3][j]=z0.w;
            Q[4][j]=z1.x; Q[5][j]=z1.y; Q[6][j]=z1.z; Q[7][j]=z1.w;
        }
    } else {
        #pragma unroll
        for (int m = 0; m < NMODE; ++m) {
            Q[m][0] = Q[m][1] = Q[m][2] = 0.f;
            Pp[m] = 1.0f;
        }
    }

    const size_t nOut = (size_t)B * T_LEN * 9;

    #pragma unroll 2
    for (int s = 0; s < L; ++s) {
        size_t row = (size_t)b * T_LEN + (t0 + s);
        const float* p = pp + row * NPP;

        float tau_c[NMODE], g_c[NMODE];
        #pragma unroll
        for (int m = 0; m < NMODE; ++m) tau_c[m] = p[m];
        float g8 = p[8];
        #pragma unroll
        for (int m = 0; m < NMODE; ++m) g_c[m] = p[9 + m];
        float t_c = tt[row];
        const float* sc = Se + row * 9 + e0;
        float S_c[3] = { sc[0], sc[1], sc[2] };

        float gsum = g8;
        #pragma unroll
        for (int m = 0; m < NMODE; ++m) gsum += g_c[m];
        float inv_c = __builtin_amdgcn_rcpf(gsum);

        float ndt = t_p - t_c;                       // -dt
        float dS[3] = { S_c[0]-S_p[0], S_c[1]-S_p[1], S_c[2]-S_p[2] };
        float qs0 = 0.f, qs1 = 0.f, qs2 = 0.f;

        #pragma unroll
        for (int m = 0; m < NMODE; ++m) {
            float ee  = __expf(ndt * __builtin_amdgcn_rcpf(tau_c[m] + tau_p[m]));
            float A   = ee * ee;
            float g_b = 0.5f * (g_c[m] * inv_c + g_p[m] * inv_p);
            float eC  = ee * g_b;
            Q[m][0] = A * Q[m][0] + eC * dS[0];
            Q[m][1] = A * Q[m][1] + eC * dS[1];
            Q[m][2] = A * Q[m][2] + eC * dS[2];
            if (!PHASE3) Pp[m] *= A;
            else { qs0 += Q[m][0]; qs1 += Q[m][1]; qs2 += Q[m][2]; }
            tau_p[m] = tau_c[m];
            g_p[m]   = g_c[m];
        }
        inv_p = inv_c;
        t_p   = t_c;
        S_p[0] = S_c[0]; S_p[1] = S_c[1]; S_p[2] = S_c[2];

        if (PHASE3) {
            size_t sidx = row * 9 + (size_t)e0;
            float gi = g8 * inv_c;
            float sf0 = gi * S_c[0], sf1 = gi * S_c[1], sf2 = gi * S_c[2];
            out[sidx]     = sf0 + qs0;
            out[sidx + 1] = sf1 + qs1;
            out[sidx + 2] = sf2 + qs2;
            out[nOut + sidx]     = sf0;
            out[nOut + sidx + 1] = sf1;
            out[nOut + sidx + 2] = sf2;
            out[2*nOut + sidx]     = qs0;
            out[2*nOut + sidx + 1] = qs1;
            out[2*nOut + sidx + 2] = qs2;
        }
    }

    if (!PHASE3) {
        #pragma unroll
        for (int j = 0; j < 3; ++j) {
            size_t rb = ((size_t)(b * 9 + e0 + j) * NC + (size_t)c) * NMODE;
            float4* rz = (float4*)(R + rb);
            rz[0] = make_float4(Q[0][j], Q[1][j], Q[2][j], Q[3][j]);
            rz[1] = make_float4(Q[4][j], Q[5][j], Q[6][j], Q[7][j]);
        }
        if (eg == 0) {
            float4* pz = (float4*)(P + ((size_t)b * NC + (size_t)c) * NMODE);
            pz[0] = make_float4(Pp[0], Pp[1], Pp[2], Pp[3]);
            pz[1] = make_float4(Pp[4], Pp[5], Pp[6], Pp[7]);
        }
    }
}

// ---------------------------------------------------------------------------
// Inter-chunk scan: ONE WAVE per (b,e). Lane l owns K consecutive chunks
// (contiguous 32B each, 32*K B per lane — fully coalesced). Lane-local affine
// compose, 6-step shfl_up butterfly on the 16-float (P,R) state, exclusive
// shift, replay writes per-chunk entry states Z back into R.
// ---------------------------------------------------------------------------
template <int K>
__global__ __launch_bounds__(256)
void chunk_scan_wave(float* __restrict__ R, const float* __restrict__ P,
                     int B) {
    constexpr int NC = K * 64;
    int gtid = blockIdx.x * blockDim.x + threadIdx.x;
    int wid  = gtid >> 6;
    int lane = gtid & 63;
    if (wid >= B * 9) return;
    int e = wid % 9;
    int b = wid / 9;

    float* rp       = R + ((size_t)(b * 9 + e) * NC) * NMODE;
    const float* pq = P + ((size_t)b * NC) * NMODE;

    float pk[K][NMODE], rk[K][NMODE];
    float pa[NMODE], ra[NMODE];
    #pragma unroll
    for (int m = 0; m < NMODE; ++m) { pa[m] = 1.f; ra[m] = 0.f; }

    #pragma unroll
    for (int k = 0; k < K; ++k) {
        int c = lane * K + k;
        const float4* rv = (const float4*)(rp + (size_t)c * NMODE);
        const float4* pv = (const float4*)(pq + (size_t)c * NMODE);
        float4 r0 = rv[0], r1 = rv[1], p0 = pv[0], p1 = pv[1];
        rk[k][0]=r0.x; rk[k][1]=r0.y; rk[k][2]=r0.z; rk[k][3]=r0.w;
        rk[k][4]=r1.x; rk[k][5]=r1.y; rk[k][6]=r1.z; rk[k][7]=r1.w;
        pk[k][0]=p0.x; pk[k][1]=p0.y; pk[k][2]=p0.z; pk[k][3]=p0.w;
        pk[k][4]=p1.x; pk[k][5]=p1.y; pk[k][6]=p1.z; pk[k][7]=p1.w;
        #pragma unroll
        for (int m = 0; m < NMODE; ++m) {
            ra[m] = pk[k][m] * ra[m] + rk[k][m];
            pa[m] = pk[k][m] * pa[m];
        }
    }

    #pragma unroll
    for (int d = 1; d < 64; d <<= 1) {
        #pragma unroll
        for (int m = 0; m < NMODE; ++m) {
            float plo = __shfl_up(pa[m], d);
            float rlo = __shfl_up(ra[m], d);
            if (lane >= d) {
                ra[m] = pa[m] * rlo + ra[m];
                pa[m] = pa[m] * plo;
            }
        }
    }

    float z[NMODE];
    #pragma unroll
    for (int m = 0; m < NMODE; ++m) {
        float zz = __shfl_up(ra[m], 1);
        z[m] = (lane == 0) ? 0.f : zz;
    }

    #pragma unroll
    for (int k = 0; k < K; ++k) {
        int c = lane * K + k;
        float4* rv = (float4*)(rp + (size_t)c * NMODE);
        rv[0] = make_float4(z[0], z[1], z[2], z[3]);
        rv[1] = make_float4(z[4], z[5], z[6], z[7]);
        #pragma unroll
        for (int m = 0; m < NMODE; ++m)
            z[m] = pk[k][m] * z[m] + rk[k][m];
    }
}

// ---------------------------------------------------------------------------
template <int L>
static void run_pipeline(const float* Se, const float* tt, const float* pp,
                         float* out, float* ws, int B, hipStream_t stream) {
    constexpr int NC = T_LEN / L;
    constexpr int K  = NC / 64;
    float* R = ws;
    float* P = R + (size_t)B * 9 * NC * NMODE;

    int tot1  = B * NC * 3;
    int grid1 = (tot1 + 127) / 128;
    int tot2  = B * 9 * 64;                 // one wave per (b,e)
    int grid2 = (tot2 + 255) / 256;

    scan_fused3<L, false><<<grid1, dim3(128), 0, stream>>>(Se, tt, pp, R, P, nullptr, B);
    chunk_scan_wave<K><<<grid2, dim3(256), 0, stream>>>(R, P, B);
    scan_fused3<L, true><<<grid1, dim3(128), 0, stream>>>(Se, tt, pp, R, P, out, B);
}

extern "C" void kernel_launch(void* const* d_in, const int* in_sizes, int n_in,
                              void* d_out, int out_size, void* d_ws, size_t ws_size,
                              hipStream_t stream) {
    const float* Se = (const float*)d_in[0];
    const float* tt = (const float*)d_in[1];
    const float* pp = (const float*)d_in[2];
    float* out = (float*)d_out;
    float* ws  = (float*)d_ws;

    int B = in_sizes[1] / T_LEN;

    auto need = [&](int NC) {
        return ((size_t)B * 9 * NC * NMODE + (size_t)B * NC * NMODE) * sizeof(float);
    };

    if (need(T_LEN / 4) <= ws_size) {
        run_pipeline<4>(Se, tt, pp, out, ws, B, stream);     // NC=512, K=8
    } else if (need(T_LEN / 8) <= ws_size) {
        run_pipeline<8>(Se, tt, pp, out, ws, B, stream);     // NC=256, K=4
    } else if (need(T_LEN / 16) <= ws_size) {
        run_pipeline<16>(Se, tt, pp, out, ws, B, stream);    // NC=128, K=2
    } else {
        run_pipeline<32>(Se, tt, pp, out, ws, B, stream);    // NC=64,  K=1
    }
}